// Round 1
// baseline (422.148 us; speedup 1.0000x reference)
//
#include <hip/hip_runtime.h>
#include <hip/hip_bf16.h>

// 6-level 2D DB4 wavelet (forward -> soft threshold -> inverse), N=4096 fp32.
// Circular convolution done directly in spatial domain (8-tap), sizes all pow2.
//
// d_out layout: [0 .. 16777216) reconstruction, [16777216 .. 33554432) flat coeffs.
// Flat per level: row i = [hh_i | hl_i | lh_i], row stride 3*sc. Final thr(approx)
// (64x64) at the end. Thresholded coeffs are written to flat during forward and
// read back during inverse.
//
// ws layout (floats): A1(4194304) A2(1048576) A3(262144) A4(65536) A5(16384)
// A6(4096) | H(8388608) | L(8388608)  => 89,473,024 bytes total.
// Forward row-pass tmps + inverse approx ping-pong live inside d_out's recon
// region (free until the last inverse kernel, which reads only ws H/L).

__device__ __forceinline__ float thrf(float t, float alpha, float bp, float bm) {
    // t * (sigmoid(alpha*(t-bp)) + sigmoid(-alpha*(t+bm)))
    float s1 = 1.0f / (1.0f + __expf(-alpha * (t - bp)));
    float s2 = 1.0f / (1.0f + __expf( alpha * (t + bm)));
    return t * (s1 + s2);
}

__device__ __forceinline__ void load_filt(const float* __restrict__ filt,
                                          float (&h)[8], float (&w)[8]) {
#pragma unroll
    for (int k = 0; k < 8; ++k) h[k] = filt[k];
#pragma unroll
    for (int k = 0; k < 8; ++k) w[k] = (k & 1) ? -h[7 - k] : h[7 - k];
}

// Row pass: X (s x s) -> D,A (s x sh), sh = s/2.
// d[i,j] = sum_k w[k]*X[i, (2j-k) mod s]; a likewise with h.
__global__ void fwd_row_kernel(const float* __restrict__ X, int s, int sh,
                               float* __restrict__ D, float* __restrict__ A,
                               const float* __restrict__ filt) {
    int j = blockIdx.x * blockDim.x + threadIdx.x;
    int i = blockIdx.y;
    if (j >= sh) return;
    float h[8], w[8];
    load_filt(filt, h, w);
    const float* row = X + (size_t)i * s;
    int base = 2 * j;
    float d = 0.f, a = 0.f;
#pragma unroll
    for (int k = 0; k < 8; ++k) {
        float v = row[(base - k) & (s - 1)];
        d += w[k] * v;
        a += h[k] * v;
    }
    D[(size_t)i * sh + j] = d;
    A[(size_t)i * sh + j] = a;
}

// Column pass: S (s x sh) -> outW[i*strideW + j] = (thr of) w-filtered,
// outH[i*strideH + j] = (thr if thrH) h-filtered; i in [0,sh), j in [0,sh).
__global__ void fwd_col_kernel(const float* __restrict__ S, int s, int sh,
                               float* __restrict__ outW, int strideW,
                               float* __restrict__ outH, int strideH, int thrH,
                               const float* __restrict__ filt,
                               const float* __restrict__ ap,
                               const float* __restrict__ bpp,
                               const float* __restrict__ bmp) {
    int j = blockIdx.x * blockDim.x + threadIdx.x;
    int i = blockIdx.y;
    if (j >= sh) return;
    float h[8], w[8];
    load_filt(filt, h, w);
    float alpha = *ap, bp = *bpp, bm = *bmp;
    int base = 2 * i;
    float dv = 0.f, av = 0.f;
#pragma unroll
    for (int k = 0; k < 8; ++k) {
        float v = S[(size_t)((base - k) & (s - 1)) * sh + j];
        dv += w[k] * v;
        av += h[k] * v;
    }
    outW[(size_t)i * strideW + j] = thrf(dv, alpha, bp, bm);
    outH[(size_t)i * strideH + j] = thrH ? thrf(av, alpha, bp, bm) : av;
}

// Elementwise threshold (final approx).
__global__ void thr_kernel(const float* __restrict__ in, float* __restrict__ out,
                           int n, const float* __restrict__ ap,
                           const float* __restrict__ bpp,
                           const float* __restrict__ bmp) {
    int idx = blockIdx.x * blockDim.x + threadIdx.x;
    if (idx >= n) return;
    out[idx] = thrf(in[idx], *ap, *bpp, *bmp);
}

// Column inverse: det,app are (sc x sc) with row strides dstride/astride.
// out (2sc x sc): out[n,j] = sum over upsampled circular correlation taps.
__global__ void inv_col_kernel(const float* __restrict__ det, int dstride,
                               const float* __restrict__ app, int astride,
                               int sc, float* __restrict__ out,
                               const float* __restrict__ filt) {
    int j = blockIdx.x * blockDim.x + threadIdx.x;
    int n = blockIdx.y;  // 0 .. 2sc-1
    if (j >= sc) return;
    float h[8], w[8];
    load_filt(filt, h, w);
    int half = n >> 1;
    float acc = 0.f;
    if ((n & 1) == 0) {
#pragma unroll
        for (int t = 0; t < 4; ++t) {
            int m = (half + t) & (sc - 1);
            acc += w[2 * t] * det[(size_t)m * dstride + j]
                 + h[2 * t] * app[(size_t)m * astride + j];
        }
    } else {
#pragma unroll
        for (int t = 0; t < 4; ++t) {
            int m = (half + t + 1) & (sc - 1);
            acc += w[2 * t + 1] * det[(size_t)m * dstride + j]
                 + h[2 * t + 1] * app[(size_t)m * astride + j];
        }
    }
    out[(size_t)n * sc + j] = acc;
}

// Row inverse: Hd,La (r x sc) -> out (r x 2sc).
__global__ void inv_row_kernel(const float* __restrict__ Hd,
                               const float* __restrict__ La,
                               int r, int sc, float* __restrict__ out,
                               const float* __restrict__ filt) {
    int m = blockIdx.x * blockDim.x + threadIdx.x;  // 0 .. 2sc-1
    int i = blockIdx.y;
    if (m >= 2 * sc) return;
    float h[8], w[8];
    load_filt(filt, h, w);
    const float* hrow = Hd + (size_t)i * sc;
    const float* lrow = La + (size_t)i * sc;
    int half = m >> 1;
    float acc = 0.f;
    if ((m & 1) == 0) {
#pragma unroll
        for (int t = 0; t < 4; ++t) {
            int idx = (half + t) & (sc - 1);
            acc += w[2 * t] * hrow[idx] + h[2 * t] * lrow[idx];
        }
    } else {
#pragma unroll
        for (int t = 0; t < 4; ++t) {
            int idx = (half + t + 1) & (sc - 1);
            acc += w[2 * t + 1] * hrow[idx] + h[2 * t + 1] * lrow[idx];
        }
    }
    out[(size_t)i * 2 * sc + m] = acc;
}

extern "C" void kernel_launch(void* const* d_in, const int* in_sizes, int n_in,
                              void* d_out, int out_size, void* d_ws, size_t ws_size,
                              hipStream_t stream) {
    const float* x    = (const float*)d_in[0];
    const float* scal = (const float*)d_in[1];  // 12 x 8
    const float* ap   = (const float*)d_in[2];
    const float* bp   = (const float*)d_in[3];
    const float* bm   = (const float*)d_in[4];
    float* out = (float*)d_out;
    float* ws  = (float*)d_ws;

    const int N = 4096;
    float* recon = out;
    float* flat  = out + 16777216;
    float* tmpD  = out;            // forward row-pass tmp (8M floats)
    float* tmpA  = out + 8388608;  // forward row-pass tmp (8M floats)

    // ws offsets (floats)
    static const size_t Aoff[7] = {0, 0, 4194304, 5242880, 5505024, 5570560, 5586944};
    const size_t Hoff = 5591040;
    const size_t Loff = 13979648;
    static const size_t flatOff[6] = {0, 12582912, 15728640, 16515072, 16711680, 16760832};
    const size_t finalOff = 16773120;

    dim3 blk(256);

    // ---------------- Forward ----------------
    const float* src = x;
    for (int lev = 0; lev < 6; ++lev) {
        int s = N >> lev, sh = s >> 1;
        dim3 grow((sh + 255) / 256, s);
        fwd_row_kernel<<<grow, blk, 0, stream>>>(src, s, sh, tmpD, tmpA, scal + lev * 8);

        dim3 gcol((sh + 255) / 256, sh);
        float* fl = flat + flatOff[lev];
        // detail branch: hh (w, thr) and hl (h, thr) into flat, row stride 3*sh
        fwd_col_kernel<<<gcol, blk, 0, stream>>>(tmpD, s, sh,
                                                 fl, 3 * sh, fl + sh, 3 * sh, 1,
                                                 scal + (lev + 1) * 8, ap, bp, bm);
        // approx branch: lh (w, thr) into flat; ll (h, raw) -> next approx in ws
        float* All = ws + Aoff[lev + 1];
        fwd_col_kernel<<<gcol, blk, 0, stream>>>(tmpA, s, sh,
                                                 fl + 2 * sh, 3 * sh, All, sh, 0,
                                                 scal + (lev + 1) * 8, ap, bp, bm);
        src = All;
    }
    // threshold final approx (64x64) into flat tail
    thr_kernel<<<dim3(16), blk, 0, stream>>>(ws + Aoff[6], flat + finalOff, 4096,
                                             ap, bp, bm);

    // ---------------- Inverse ----------------
    const float* a_in = flat + finalOff;
    for (int lev = 5; lev >= 0; --lev) {
        int sc = N >> (lev + 1), r = 2 * sc;
        const float* fl = flat + flatOff[lev];
        float* Hb = ws + Hoff;
        float* Lb = ws + Loff;
        dim3 gc((sc + 255) / 256, r);
        // h = invcol(det=hh, app=hl)
        inv_col_kernel<<<gc, blk, 0, stream>>>(fl, 3 * sc, fl + sc, 3 * sc, sc, Hb,
                                               scal + (lev + 1) * 8);
        // l = invcol(det=lh, app=a)
        inv_col_kernel<<<gc, blk, 0, stream>>>(fl + 2 * sc, 3 * sc, a_in, sc, sc, Lb,
                                               scal + (lev + 1) * 8);
        // row inverse -> next approx (ping-pong in recon region; last writes recon)
        float* outp = (lev == 0) ? recon : ((lev & 1) ? out : out + 4194304);
        dim3 gr((r + 255) / 256, r);
        inv_row_kernel<<<gr, blk, 0, stream>>>(Hb, Lb, r, sc, outp, scal + lev * 8);
        a_in = outp;
    }
}

// Round 2
// 342.055 us; speedup vs baseline: 1.2341x; 1.2341x over previous
//
#include <hip/hip_runtime.h>
#include <hip/hip_bf16.h>

// 6-level 2D DB4 wavelet (forward -> soft threshold -> inverse), N=4096 fp32.
// R2: fused per-level kernels (row+col filter through LDS). 13 launches total.
//
// d_out layout: [0 .. 16777216) reconstruction, [16777216 .. 33554432) flat coeffs.
// Flat per level: row i = [hh_i | hl_i | lh_i], row stride 3*sc; final thr(approx)
// (64x64) at the tail.
//
// ws layout (floats): approx chain A1..A6 [0 .. 5591040) | P0 (4194304) | P1 (4194304)
// => 55.9 MB (round 1 proved ws >= 85 MB).

__device__ __forceinline__ float thrf(float t, float alpha, float bp, float bm) {
    float s1 = 1.0f / (1.0f + __expf(-alpha * (t - bp)));
    float s2 = 1.0f / (1.0f + __expf( alpha * (t + bm)));
    return t * (s1 + s2);
}

__device__ __forceinline__ void load_filt(const float* __restrict__ filt,
                                          float (&h)[8], float (&w)[8]) {
#pragma unroll
    for (int k = 0; k < 8; ++k) h[k] = filt[k];
#pragma unroll
    for (int k = 0; k < 8; ++k) w[k] = (k & 1) ? -h[7 - k] : h[7 - k];
}

// Fused forward level: X (s x s) -> thresholded hh|hl|lh into flat (stride 3*sh)
// + raw ll into All (stride sh). 32x32 output tile per block.
__global__ __launch_bounds__(256) void fwd_fused(
    const float* __restrict__ X, int s, int sh,
    float* __restrict__ flat, float* __restrict__ All,
    const float* __restrict__ filt_row, const float* __restrict__ filt_col,
    const float* __restrict__ ap, const float* __restrict__ bpp,
    const float* __restrict__ bmp) {
    __shared__ float xs[72][73];
    __shared__ float Ds[72][33];
    __shared__ float As[72][33];
    const int tid = threadIdx.x;
    const int j0 = blockIdx.x * 32, i0 = blockIdx.y * 32;
    float hr[8], wr[8], hc[8], wc[8];
    load_filt(filt_row, hr, wr);
    load_filt(filt_col, hc, wc);
    const int sm = s - 1;
    // load input tile with circular halo: rows 2*i0-7 .. 2*i0+64, cols likewise
    for (int idx = tid; idx < 72 * 72; idx += 256) {
        int rr = idx / 72, cc = idx - rr * 72;
        int gr = (2 * i0 - 7 + rr) & sm;
        int gc = (2 * j0 - 7 + cc) & sm;
        xs[rr][cc] = X[(size_t)gr * s + gc];
    }
    __syncthreads();
    // row filter: D/A[rr][j], local col c = 2j+7-k
    for (int idx = tid; idx < 72 * 32; idx += 256) {
        int rr = idx >> 5, j = idx & 31;
        float d = 0.f, a = 0.f;
#pragma unroll
        for (int k = 0; k < 8; ++k) {
            float v = xs[rr][2 * j + 7 - k];
            d += wr[k] * v;
            a += hr[k] * v;
        }
        Ds[rr][j] = d;
        As[rr][j] = a;
    }
    __syncthreads();
    const float alpha = *ap, bp = *bpp, bm = *bmp;
    // col filter + threshold + store
    for (int idx = tid; idx < 32 * 32; idx += 256) {
        int i = idx >> 5, j = idx & 31;
        float hh = 0.f, hl = 0.f, lh = 0.f, ll = 0.f;
#pragma unroll
        for (int k = 0; k < 8; ++k) {
            float dv = Ds[2 * i + 7 - k][j];
            float av = As[2 * i + 7 - k][j];
            hh += wc[k] * dv;
            hl += hc[k] * dv;
            lh += wc[k] * av;
            ll += hc[k] * av;
        }
        size_t ro = (size_t)(i0 + i) * (3 * sh) + (j0 + j);
        flat[ro]          = thrf(hh, alpha, bp, bm);
        flat[ro + sh]     = thrf(hl, alpha, bp, bm);
        flat[ro + 2 * sh] = thrf(lh, alpha, bp, bm);
        All[(size_t)(i0 + i) * sh + (j0 + j)] = ll;
    }
}

__global__ void thr_kernel(const float* __restrict__ in, float* __restrict__ out,
                           int n, const float* __restrict__ ap,
                           const float* __restrict__ bpp,
                           const float* __restrict__ bmp) {
    int idx = blockIdx.x * blockDim.x + threadIdx.x;
    if (idx >= n) return;
    out[idx] = thrf(in[idx], *ap, *bpp, *bmp);
}

// Fused inverse level: hh|hl|lh from flat (stride 3*sc) + a (stride sc)
// -> out tile 64x64 full-res (stride ostride). Col inverse (filt_col) then
// row inverse (filt_row) through LDS.
__global__ __launch_bounds__(256) void inv_fused(
    const float* __restrict__ flatl, const float* __restrict__ a, int astride,
    int sc, float* __restrict__ outp, int ostride,
    const float* __restrict__ filt_col, const float* __restrict__ filt_row) {
    __shared__ float hhs[36][37], hls[36][37], lhs[36][37], as_[36][37];
    __shared__ float Hs[64][37], Ls[64][37];
    const int tid = threadIdx.x;
    const int m0 = blockIdx.x * 64, i0 = blockIdx.y * 64;
    float hr[8], wr[8], hc[8], wc[8];
    load_filt(filt_row, hr, wr);
    load_filt(filt_col, hc, wc);
    const int mm = sc - 1;
    const int r0 = i0 >> 1, c0 = m0 >> 1;
    const int ds = 3 * sc;
    // load 36x36 tiles of all four coefficient arrays (wrap at load)
    for (int idx = tid; idx < 36 * 36; idx += 256) {
        int rr = idx / 36, cc = idx - rr * 36;
        int gr = (r0 + rr) & mm;
        int gc = (c0 + cc) & mm;
        size_t fo = (size_t)gr * ds + gc;
        hhs[rr][cc] = flatl[fo];
        hls[rr][cc] = flatl[fo + sc];
        lhs[rr][cc] = flatl[fo + 2 * sc];
        as_[rr][cc] = a[(size_t)gr * astride + gc];
    }
    __syncthreads();
    // col inverse: H from (hh,hl), L from (lh,a); rows n = i0..i0+63
    for (int idx = tid; idx < 64 * 36; idx += 256) {
        int n = idx / 36, jj = idx - (idx / 36) * 36;
        int nh = n >> 1;
        float Hv = 0.f, Lv = 0.f;
        if ((n & 1) == 0) {
#pragma unroll
            for (int t = 0; t < 4; ++t) {
                int lr = nh + t;
                Hv += wc[2 * t] * hhs[lr][jj] + hc[2 * t] * hls[lr][jj];
                Lv += wc[2 * t] * lhs[lr][jj] + hc[2 * t] * as_[lr][jj];
            }
        } else {
#pragma unroll
            for (int t = 0; t < 4; ++t) {
                int lr = nh + t + 1;
                Hv += wc[2 * t + 1] * hhs[lr][jj] + hc[2 * t + 1] * hls[lr][jj];
                Lv += wc[2 * t + 1] * lhs[lr][jj] + hc[2 * t + 1] * as_[lr][jj];
            }
        }
        Hs[n][jj] = Hv;
        Ls[n][jj] = Lv;
    }
    __syncthreads();
    // row inverse -> 64x64 output tile
    for (int idx = tid; idx < 64 * 64; idx += 256) {
        int i = idx >> 6, m = idx & 63;
        int mh = m >> 1;
        float acc = 0.f;
        if ((m & 1) == 0) {
#pragma unroll
            for (int t = 0; t < 4; ++t) {
                int lc = mh + t;
                acc += wr[2 * t] * Hs[i][lc] + hr[2 * t] * Ls[i][lc];
            }
        } else {
#pragma unroll
            for (int t = 0; t < 4; ++t) {
                int lc = mh + t + 1;
                acc += wr[2 * t + 1] * Hs[i][lc] + hr[2 * t + 1] * Ls[i][lc];
            }
        }
        outp[(size_t)(i0 + i) * ostride + (m0 + m)] = acc;
    }
}

extern "C" void kernel_launch(void* const* d_in, const int* in_sizes, int n_in,
                              void* d_out, int out_size, void* d_ws, size_t ws_size,
                              hipStream_t stream) {
    const float* x    = (const float*)d_in[0];
    const float* scal = (const float*)d_in[1];  // 12 x 8
    const float* ap   = (const float*)d_in[2];
    const float* bp   = (const float*)d_in[3];
    const float* bm   = (const float*)d_in[4];
    float* out = (float*)d_out;
    float* ws  = (float*)d_ws;

    const int N = 4096;
    float* recon = out;
    float* flat  = out + 16777216;

    // ws offsets (floats)
    static const size_t Aoff[7] = {0, 0, 4194304, 5242880, 5505024, 5570560, 5586944};
    static const size_t flatOff[6] = {0, 12582912, 15728640, 16515072, 16711680, 16760832};
    const size_t finalOff = 16773120;
    float* P0 = ws + 5591040;
    float* P1 = ws + 5591040 + 4194304;

    dim3 blk(256);

    // ---------------- Forward (6 fused kernels) ----------------
    const float* src = x;
    for (int lev = 0; lev < 6; ++lev) {
        int s = N >> lev, sh = s >> 1;
        dim3 g(sh / 32, sh / 32);
        fwd_fused<<<g, blk, 0, stream>>>(src, s, sh, flat + flatOff[lev],
                                         ws + Aoff[lev + 1],
                                         scal + lev * 8, scal + (lev + 1) * 8,
                                         ap, bp, bm);
        src = ws + Aoff[lev + 1];
    }
    // threshold final approx (64x64) into flat tail
    thr_kernel<<<dim3(16), blk, 0, stream>>>(ws + Aoff[6], flat + finalOff, 4096,
                                             ap, bp, bm);

    // ---------------- Inverse (6 fused kernels) ----------------
    const float* a_in = flat + finalOff;
    for (int lev = 5; lev >= 0; --lev) {
        int sc = N >> (lev + 1), r = 2 * sc;
        float* outp = (lev == 0) ? recon : ((lev & 1) ? P1 : P0);
        dim3 g(r / 64, r / 64);
        inv_fused<<<g, blk, 0, stream>>>(flat + flatOff[lev], a_in, sc,
                                         sc, outp, r,
                                         scal + (lev + 1) * 8, scal + lev * 8);
        a_in = outp;
    }
}